// Round 3
// baseline (3425.638 us; speedup 1.0000x reference)
//
#include <hip/hip_runtime.h>
#include <math.h>

#define NPTS   20001
#define NREAL  20000
#define EPAD   1200000
#define KK     64
#define RADF   0.1125f

__device__ __forceinline__ float sgnf(float v){ return v>0.f ? 1.f : (v<0.f ? -1.f : 0.f); }

// ---------------- CSR build (edge_src is sorted; pad edges have dst==NREAL) ----------------
__global__ void k_find_ereal(const int* __restrict__ dst, int* __restrict__ ereal){
  int lo=0, hi=EPAD;
  while(lo<hi){ int mid=(lo+hi)>>1; if(dst[mid]==NREAL) hi=mid; else lo=mid+1; }
  *ereal = lo;
}

__global__ void k_csr(const int* __restrict__ src, const int* __restrict__ erealp,
                      int* __restrict__ row_start){
  int i = blockIdx.x*blockDim.x + threadIdx.x;
  if(i > NPTS) return;
  int E = *erealp;
  int lo=0, hi=E;
  while(lo<hi){ int mid=(lo+hi)>>1; if(src[mid] < i) lo=mid+1; else hi=mid; }
  row_start[i] = lo;
}

__global__ void k_build_f(const float* __restrict__ feats, float* __restrict__ f){
  int idx = blockIdx.x*blockDim.x + threadIdx.x;
  if(idx >= NPTS*13) return;
  int i = idx/13, c = idx - i*13;
  f[idx] = (c==0) ? 1.f : feats[i*12 + (c-1)];
}

// ---------------- per-edge geometry (exact port of ball_to_cube + window) ----------------
__device__ __forceinline__ void edge_geom(float ox, float oy, float oz,
                                          float& win, float& t0, float& t1, float& t2, int& f0p){
  const float eps = 1e-9f;
  float sq = ox*ox + oy*oy + oz*oz;
  float u = 1.f - sq;
  win = fminf(fmaxf(u*u*u, 0.f), 1.f);
  float norm = sqrtf(sq + eps);
  float rxy2 = ox*ox + oy*oy;
  bool polar = (1.25f*oz*oz > rxy2);
  float s_p = sqrtf(3.f*norm/(norm + fabsf(oz) + eps));
  float s_n = norm / sqrtf(rxy2 + eps);
  float s = polar ? s_p : s_n;
  float xc = ox*s, yc = oy*s;
  float zc = polar ? sgnf(oz)*norm : 1.5f*oz;
  if(sq < 1e-12f){ xc = 0.f; yc = 0.f; zc = 0.f; }
  float r = sqrtf(xc*xc + yc*yc + eps);
  bool c1 = fabsf(xc) >= fabsf(yc);
  float xs = (fabsf(xc) < eps) ? eps : xc;
  float ys = (fabsf(yc) < eps) ? eps : yc;
  const float fop = 1.2732395447351628f; // float32(4/pi)
  float a = c1 ? sgnf(xc)*r : sgnf(yc)*r*fop*atanf(xc/ys);
  float b = c1 ? sgnf(xc)*r*fop*atanf(yc/xs) : sgnf(yc)*r;
  if(xc*xc + yc*yc < 1e-12f){ a = 0.f; b = 0.f; }
  float g0 = fminf(fmaxf((a *0.5f+0.5f)*3.f, 0.f), 3.f);
  float g1 = fminf(fmaxf((b *0.5f+0.5f)*3.f, 0.f), 3.f);
  float g2 = fminf(fmaxf((zc*0.5f+0.5f)*3.f, 0.f), 3.f);
  float f00 = floorf(g0), f01 = floorf(g1), f02 = floorf(g2);
  t0 = g0 - f00; t1 = g1 - f01; t2 = g2 - f02;
  f0p = (int)f00 | ((int)f01 << 2) | ((int)f02 << 4);
}

// ---------------- scatter for CIN=13 (odd, 1 channel/lane, NG=2 private copies) --------
__global__ __launch_bounds__(128) void k_scat1(
    const float* __restrict__ feat, const float* __restrict__ pos,
    const int* __restrict__ edst, const int* __restrict__ row_start,
    float* __restrict__ B, int node_base)
{
  constexpr int CIN = 13;
  constexpr int BSZ = KK*CIN;
  __shared__ __align__(16) float Bl[2*BSZ];
  __shared__ float g_win[128], g_t0[128], g_t1[128], g_t2[128];
  __shared__ int   g_f0[128], g_dst[128];
  const int tid  = threadIdx.x;
  const int node = node_base + blockIdx.x;

  for(int j = tid*4; j < 2*BSZ; j += 512)
    *(float4*)&Bl[j] = make_float4(0.f,0.f,0.f,0.f);

  const int e0 = row_start[node], e1 = row_start[node+1];
  const float px = pos[node*3+0], py = pos[node*3+1], pz = pos[node*3+2];
  const int g = tid>>6, c = tid&63;
  const bool act = (c < CIN);
  float* Bp = Bl + g*BSZ;
  __syncthreads();

  for(int eb = e0; eb < e1; eb += 128){
    const int m = min(128, e1 - eb);
    if(tid < m){
      const int e = eb + tid;
      const int d = edst[e];
      float ox = (pos[d*3+0]-px)/RADF;
      float oy = (pos[d*3+1]-py)/RADF;
      float oz = (pos[d*3+2]-pz)/RADF;
      float win, t0, t1, t2; int f0p;
      edge_geom(ox, oy, oz, win, t0, t1, t2, f0p);
      g_dst[tid]=d; g_win[tid]=win; g_t0[tid]=t0; g_t1[tid]=t1; g_t2[tid]=t2; g_f0[tid]=f0p;
    }
    __syncthreads();
    if(act){
      for(int j = g; j < m; j += 2){
        const float win = g_win[j];
        if(win <= 0.f) continue;
        const float t0 = g_t0[j], t1 = g_t1[j], t2 = g_t2[j];
        const int f0 = g_f0[j];
        float v = feat[(size_t)g_dst[j]*CIN + c];
        const int i0 = f0 & 3, i1 = (f0>>2) & 3, i2 = f0 >> 4;
        const int i0p = min(i0+1,3), i1p = min(i1+1,3), i2p = min(i2+1,3);
        const float wx0 = win*(1.f-t0), wx1 = win*t0;
        const float wy0 = 1.f-t1, wy1 = t1;
        const float wz0 = 1.f-t2, wz1 = t2;
        Bp[((i0 <<4)|(i1 <<2)|i2 )*CIN + c] += (wx0*wy0*wz0) * v;
        Bp[((i0 <<4)|(i1 <<2)|i2p)*CIN + c] += (wx0*wy0*wz1) * v;
        Bp[((i0 <<4)|(i1p<<2)|i2 )*CIN + c] += (wx0*wy1*wz0) * v;
        Bp[((i0 <<4)|(i1p<<2)|i2p)*CIN + c] += (wx0*wy1*wz1) * v;
        Bp[((i0p<<4)|(i1 <<2)|i2 )*CIN + c] += (wx1*wy0*wz0) * v;
        Bp[((i0p<<4)|(i1 <<2)|i2p)*CIN + c] += (wx1*wy0*wz1) * v;
        Bp[((i0p<<4)|(i1p<<2)|i2 )*CIN + c] += (wx1*wy1*wz0) * v;
        Bp[((i0p<<4)|(i1p<<2)|i2p)*CIN + c] += (wx1*wy1*wz1) * v;
      }
    }
    __syncthreads();
  }

  float* Bg = B + (size_t)blockIdx.x*BSZ;
  for(int j = tid*4; j < BSZ; j += 512){
    float4 a = *(const float4*)&Bl[j];
    float4 b2 = *(const float4*)&Bl[BSZ+j];
    a.x+=b2.x; a.y+=b2.y; a.z+=b2.z; a.w+=b2.w;
    *(float4*)&Bg[j] = a;
  }
}

// ------- scatter for even CIN: 2 channels/lane (float2 / b64 RMW), NG=2 private copies.
// OUT3=1: fused cout=3 GEMV epilogue (layer 3) -> writes out directly, B unused.
template<int CIN, int RELU, int OUT3>
__global__ __launch_bounds__(128) void k_scat2(
    const float* __restrict__ feat, const float* __restrict__ pos,
    const int* __restrict__ edst, const int* __restrict__ row_start,
    float* __restrict__ B, int node_base,
    const float* __restrict__ W3, float* __restrict__ out)
{
  constexpr int NCH2 = CIN/2;
  constexpr int BSZ = KK*CIN;
  __shared__ __align__(16) float Bl[2*BSZ];
  __shared__ float g_win[128], g_t0[128], g_t1[128], g_t2[128];
  __shared__ int   g_f0[128], g_dst[128];
  const int tid  = threadIdx.x;
  const int node = node_base + blockIdx.x;

  for(int j = tid*4; j < 2*BSZ; j += 512)
    *(float4*)&Bl[j] = make_float4(0.f,0.f,0.f,0.f);

  const int e0 = row_start[node], e1 = row_start[node+1];
  const float px = pos[node*3+0], py = pos[node*3+1], pz = pos[node*3+2];
  const int g = tid>>6, c2 = tid&63;
  const bool act = (c2 < NCH2);
  float2* Bp2 = (float2*)(Bl + g*BSZ);
  __syncthreads();

  for(int eb = e0; eb < e1; eb += 128){
    const int m = min(128, e1 - eb);
    if(tid < m){
      const int e = eb + tid;
      const int d = edst[e];
      float ox = (pos[d*3+0]-px)/RADF;
      float oy = (pos[d*3+1]-py)/RADF;
      float oz = (pos[d*3+2]-pz)/RADF;
      float win, t0, t1, t2; int f0p;
      edge_geom(ox, oy, oz, win, t0, t1, t2, f0p);
      g_dst[tid]=d; g_win[tid]=win; g_t0[tid]=t0; g_t1[tid]=t1; g_t2[tid]=t2; g_f0[tid]=f0p;
    }
    __syncthreads();
    if(act){
      // manual prefetch pipeline: load next edge's feature pair during current RMWs
      float2 v;
      if(g < m) v = ((const float2*)(feat + (size_t)g_dst[g]*CIN))[c2];
      for(int j = g; j < m; j += 2){
        float2 vn;
        if(j+2 < m) vn = ((const float2*)(feat + (size_t)g_dst[j+2]*CIN))[c2];
        const float win = g_win[j];
        if(win > 0.f){
          const float t0 = g_t0[j], t1 = g_t1[j], t2 = g_t2[j];
          const int f0 = g_f0[j];
          float vx = v.x, vy = v.y;
          if(RELU){ vx = fmaxf(vx,0.f); vy = fmaxf(vy,0.f); }
          const int i0 = f0 & 3, i1 = (f0>>2) & 3, i2 = f0 >> 4;
          const int i0p = min(i0+1,3), i1p = min(i1+1,3), i2p = min(i2+1,3);
          const float wx0 = win*(1.f-t0), wx1 = win*t0;
          const float wy0 = 1.f-t1, wy1 = t1;
          const float wz0 = 1.f-t2, wz1 = t2;
          #define ACC8(cell, w) { float2 tmp = Bp2[(cell)*NCH2 + c2]; \
                                  tmp.x = fmaf((w), vx, tmp.x); tmp.y = fmaf((w), vy, tmp.y); \
                                  Bp2[(cell)*NCH2 + c2] = tmp; }
          ACC8(((i0 <<4)|(i1 <<2)|i2 ), wx0*wy0*wz0)
          ACC8(((i0 <<4)|(i1 <<2)|i2p), wx0*wy0*wz1)
          ACC8(((i0 <<4)|(i1p<<2)|i2 ), wx0*wy1*wz0)
          ACC8(((i0 <<4)|(i1p<<2)|i2p), wx0*wy1*wz1)
          ACC8(((i0p<<4)|(i1 <<2)|i2 ), wx1*wy0*wz0)
          ACC8(((i0p<<4)|(i1 <<2)|i2p), wx1*wy0*wz1)
          ACC8(((i0p<<4)|(i1p<<2)|i2 ), wx1*wy1*wz0)
          ACC8(((i0p<<4)|(i1p<<2)|i2p), wx1*wy1*wz1)
          #undef ACC8
        }
        v = vn;
      }
    }
    __syncthreads();
  }

  if(!OUT3){
    float* Bg = B + (size_t)blockIdx.x*BSZ;
    for(int j = tid*4; j < BSZ; j += 512){
      float4 a = *(const float4*)&Bl[j];
      float4 b2 = *(const float4*)&Bl[BSZ+j];
      a.x+=b2.x; a.y+=b2.y; a.z+=b2.z; a.w+=b2.w;
      *(float4*)&Bg[j] = a;
    }
  } else {
    // fused cout=3 GEMV: out[node] += (sum_{j} B[j] * W3[j, 0..2]) / 128
    float s0=0.f, s1=0.f, s2=0.f;
    for(int j = tid; j < BSZ; j += 128){
      float v = Bl[j] + Bl[BSZ+j];
      s0 = fmaf(v, W3[j*3+0], s0);
      s1 = fmaf(v, W3[j*3+1], s1);
      s2 = fmaf(v, W3[j*3+2], s2);
    }
    g_win[tid]=s0; g_t0[tid]=s1; g_t1[tid]=s2;
    __syncthreads();
    for(int st = 64; st > 0; st >>= 1){
      if(tid < st){ g_win[tid]+=g_win[tid+st]; g_t0[tid]+=g_t0[tid+st]; g_t1[tid]+=g_t1[tid+st]; }
      __syncthreads();
    }
    if(tid == 0 && node < NREAL){
      out[node*3+0] += g_win[0]*(1.f/128.f);
      out[node*3+1] += g_t0[0]*(1.f/128.f);
      out[node*3+2] += g_t1[0]*(1.f/128.f);
    }
  }
}

// ---------------- fp32 GEMM: out[nb+i, colofs+o] += sum_k A[i,k]*W[k,o], N=64 ----------------
__global__ __launch_bounds__(128) void k_gemm(
    const float* __restrict__ A, const float* __restrict__ W,
    float* __restrict__ out, int M, int Kd, int ldout, int colofs,
    int node_base, int ktiles_per)
{
  __shared__ __align__(16) float As[16][132];
  __shared__ __align__(16) float Ws[16][64];
  const int tid = threadIdx.x;
  const int ty = tid >> 3, tx = tid & 7;
  const int mbase = blockIdx.x * 128;
  const int kt0 = blockIdx.y * ktiles_per * 16;
  const int kt1 = min(Kd, kt0 + ktiles_per*16);

  float acc[8][8];
  #pragma unroll
  for(int i=0;i<8;++i)
    #pragma unroll
    for(int j=0;j<8;++j) acc[i][j] = 0.f;

  for(int kt = kt0; kt < kt1; kt += 16){
    {
      int row = mbase + tid;
      float4 v0,v1,v2,v3;
      if(row < M){
        const float4* ap = (const float4*)(A + (size_t)row*Kd + kt);
        v0 = ap[0]; v1 = ap[1]; v2 = ap[2]; v3 = ap[3];
      } else {
        v0 = v1 = v2 = v3 = make_float4(0.f,0.f,0.f,0.f);
      }
      float av[16] = {v0.x,v0.y,v0.z,v0.w, v1.x,v1.y,v1.z,v1.w,
                      v2.x,v2.y,v2.z,v2.w, v3.x,v3.y,v3.z,v3.w};
      #pragma unroll
      for(int q=0;q<16;++q) As[q][tid] = av[q];
    }
    {
      int k = tid >> 3, col = (tid & 7) * 8;
      const float4* wp = (const float4*)(W + (size_t)(kt + k)*64 + col);
      *(float4*)&Ws[k][col]   = wp[0];
      *(float4*)&Ws[k][col+4] = wp[1];
    }
    __syncthreads();
    #pragma unroll
    for(int kk = 0; kk < 16; ++kk){
      float a[8], b[8];
      *(float4*)&a[0] = *(const float4*)&As[kk][ty*8];
      *(float4*)&a[4] = *(const float4*)&As[kk][ty*8+4];
      *(float4*)&b[0] = *(const float4*)&Ws[kk][tx*8];
      *(float4*)&b[4] = *(const float4*)&Ws[kk][tx*8+4];
      #pragma unroll
      for(int i=0;i<8;++i)
        #pragma unroll
        for(int j=0;j<8;++j) acc[i][j] = fmaf(a[i], b[j], acc[i][j]);
    }
    __syncthreads();
  }

  #pragma unroll
  for(int i=0;i<8;++i){
    int row = mbase + ty*8 + i;
    if(row >= M) continue;
    float* orow = out + (size_t)(node_base+row)*ldout + colofs + tx*8;
    #pragma unroll
    for(int j=0;j<8;++j) atomicAdd(&orow[j], acc[i][j]);
  }
}

// ---------------- dense paths ----------------
__global__ void k_dense0(const float* __restrict__ f, const float* __restrict__ dW,
                         const float* __restrict__ db, const float* __restrict__ cb0,
                         float* __restrict__ out)
{
  int idx = blockIdx.x*blockDim.x + threadIdx.x;
  if(idx >= NPTS*96) return;
  int i = idx/96, c = idx - i*96;
  if(c < 64){ out[idx] = cb0[c]; return; }
  int o = c - 64;
  float s = db[o];
  const float* row = f + (size_t)i*13;
  #pragma unroll
  for(int j=0;j<13;++j) s = fmaf(row[j], dW[j*32+o], s);
  out[idx] = s;
}

__global__ void k_dense(const float* __restrict__ in, int cin,
                        const float* __restrict__ dW, const float* __restrict__ db,
                        const float* __restrict__ cb, const float* __restrict__ resid,
                        float* __restrict__ out)
{
  int idx = blockIdx.x*blockDim.x + threadIdx.x;
  if(idx >= NPTS*64) return;
  int i = idx >> 6, o = idx & 63;
  float s = db[o] + cb[o];
  if(resid) s += resid[idx];
  const float* row = in + (size_t)i*cin;
  for(int c=0;c<cin;++c) s = fmaf(fmaxf(row[c],0.f), dW[c*64+o], s);
  out[idx] = s;
}

__global__ void k_dense3(const float* __restrict__ x2, const float* __restrict__ dW,
                         const float* __restrict__ db, const float* __restrict__ cb,
                         float* __restrict__ out)
{
  int idx = blockIdx.x*blockDim.x + threadIdx.x;
  if(idx >= NREAL*3) return;
  int i = idx/3, o = idx - i*3;
  float s = db[o] + cb[o];
  const float* row = x2 + (size_t)i*64;
  for(int c=0;c<64;++c) s = fmaf(fmaxf(row[c],0.f), dW[c*3+o], s);
  out[idx] = s * (1.f/128.f);
}

// ---------------- host ----------------
static inline size_t alup(size_t x){ return (x + 255) & ~(size_t)255; }

static inline int calc_rows(size_t bcap, int cin){
  size_t perrow = (size_t)KK * cin * 4;
  size_t r = (perrow > 0) ? bcap / perrow : 0;
  if(r >= (size_t)NPTS) return NPTS;
  r = (r / 128) * 128;
  if(r < 128) r = 128;
  return (int)r;
}

static inline dim3 gemm_grid(int m, int Kd, int ktiles_per){
  int ktot = Kd / 16;
  int yb = (ktot + ktiles_per - 1) / ktiles_per;
  return dim3((m + 127)/128, yb);
}

extern "C" void kernel_launch(void* const* d_in, const int* in_sizes, int n_in,
                              void* d_out, int out_size, void* d_ws, size_t ws_size,
                              hipStream_t stream)
{
  const float* pos   = (const float*)d_in[0];
  const float* feats = (const float*)d_in[1];
  const int*   esrc  = (const int*)d_in[2];
  const int*   edst  = (const int*)d_in[3];
  const float* c0w = (const float*)d_in[4];
  const float* c0b = (const float*)d_in[5];
  const float* d0w = (const float*)d_in[6];
  const float* d0b = (const float*)d_in[7];
  const float* c1w = (const float*)d_in[8];
  const float* c1b = (const float*)d_in[9];
  const float* d1w = (const float*)d_in[10];
  const float* d1b = (const float*)d_in[11];
  const float* c2w = (const float*)d_in[12];
  const float* c2b = (const float*)d_in[13];
  const float* d2w = (const float*)d_in[14];
  const float* d2b = (const float*)d_in[15];
  const float* c3w = (const float*)d_in[16];
  const float* c3b = (const float*)d_in[17];
  const float* d3w = (const float*)d_in[18];
  const float* d3b = (const float*)d_in[19];
  float* out = (float*)d_out;

  char* w = (char*)d_ws;
  size_t off = 0;
  float* f  = (float*)(w+off); off += alup((size_t)NPTS*13*4);
  float* x0 = (float*)(w+off); off += alup((size_t)NPTS*96*4);
  float* x1 = (float*)(w+off); off += alup((size_t)NPTS*64*4);
  float* x2 = (float*)(w+off); off += alup((size_t)NPTS*64*4);
  int* row_start = (int*)(w+off); off += alup((size_t)(NPTS+1)*4);
  int* ereal = (int*)(w+off);     off += alup(16);
  float* B = (float*)(w+off);
  size_t bcap = (ws_size > off) ? (ws_size - off) : 0;

  k_find_ereal<<<1,1,0,stream>>>(edst, ereal);
  k_csr<<<(NPTS+1+255)/256,256,0,stream>>>(esrc, ereal, row_start);
  k_build_f<<<(NPTS*13+255)/256,256,0,stream>>>(feats, f);

  // ---- layer 0: x0[:,0:64] = cconv0(f)+c0b ; x0[:,64:96] = f@d0w+d0b
  k_dense0<<<(NPTS*96+255)/256,256,0,stream>>>(f, d0w, d0b, c0b, x0);
  {
    int rows = calc_rows(bcap, 13);
    for(int base = 0; base < NPTS; base += rows){
      int m = (NPTS - base < rows) ? (NPTS - base) : rows;
      k_scat1<<<m,128,0,stream>>>(f, pos, edst, row_start, B, base);
      k_gemm<<<gemm_grid(m, 832, 7),128,0,stream>>>(B, c0w, x0, m, 832, 96, 0, base, 7);
    }
  }

  // ---- layer 1: x1 = cconv1(relu(x0)) + relu(x0)@d1w + d1b + c1b
  k_dense<<<(NPTS*64+255)/256,256,0,stream>>>(x0, 96, d1w, d1b, c1b, nullptr, x1);
  {
    int rows = calc_rows(bcap, 96);
    for(int base = 0; base < NPTS; base += rows){
      int m = (NPTS - base < rows) ? (NPTS - base) : rows;
      k_scat2<96,1,0><<<m,128,0,stream>>>(x0, pos, edst, row_start, B, base, nullptr, nullptr);
      k_gemm<<<gemm_grid(m, 6144, 16),128,0,stream>>>(B, c1w, x1, m, 6144, 64, 0, base, 16);
    }
  }

  // ---- layer 2: x2 = cconv2(relu(x1)) + relu(x1)@d2w + d2b + c2b + x1 (residual)
  k_dense<<<(NPTS*64+255)/256,256,0,stream>>>(x1, 64, d2w, d2b, c2b, x1, x2);
  {
    int rows = calc_rows(bcap, 64);
    for(int base = 0; base < NPTS; base += rows){
      int m = (NPTS - base < rows) ? (NPTS - base) : rows;
      k_scat2<64,1,0><<<m,128,0,stream>>>(x1, pos, edst, row_start, B, base, nullptr, nullptr);
      k_gemm<<<gemm_grid(m, 4096, 16),128,0,stream>>>(B, c2w, x2, m, 4096, 64, 0, base, 16);
    }
  }

  // ---- layer 3 (fused): out = dense3 part, then scatter adds conv3 GEMV directly
  k_dense3<<<(NREAL*3+255)/256,256,0,stream>>>(x2, d3w, d3b, c3b, out);
  k_scat2<64,1,1><<<NPTS,128,0,stream>>>(x2, pos, edst, row_start, nullptr, 0, c3w, out);
}

// Round 4
// 2016.728 us; speedup vs baseline: 1.6986x; 1.6986x over previous
//
#include <hip/hip_runtime.h>
#include <math.h>

#define NPTS   20001
#define NREAL  20000
#define EPAD   1200000
#define KK     64
#define RADF   0.1125f

__device__ __forceinline__ float sgnf(float v){ return v>0.f ? 1.f : (v<0.f ? -1.f : 0.f); }

// ---------------- CSR build (edge_src is sorted; pad edges have dst==NREAL) ----------------
__global__ void k_find_ereal(const int* __restrict__ dst, int* __restrict__ ereal){
  int lo=0, hi=EPAD;
  while(lo<hi){ int mid=(lo+hi)>>1; if(dst[mid]==NREAL) hi=mid; else lo=mid+1; }
  *ereal = lo;
}

__global__ void k_csr(const int* __restrict__ src, const int* __restrict__ erealp,
                      int* __restrict__ row_start){
  int i = blockIdx.x*blockDim.x + threadIdx.x;
  if(i > NPTS) return;
  int E = *erealp;
  int lo=0, hi=E;
  while(lo<hi){ int mid=(lo+hi)>>1; if(src[mid] < i) lo=mid+1; else hi=mid; }
  row_start[i] = lo;
}

__global__ void k_build_f(const float* __restrict__ feats, float* __restrict__ f){
  int idx = blockIdx.x*blockDim.x + threadIdx.x;
  if(idx >= NPTS*13) return;
  int i = idx/13, c = idx - i*13;
  f[idx] = (c==0) ? 1.f : feats[i*12 + (c-1)];
}

// ---------------- per-edge geometry (exact port of ball_to_cube + window) ----------------
__device__ __forceinline__ void edge_geom(float ox, float oy, float oz,
                                          float& win, float& t0, float& t1, float& t2, int& f0p){
  const float eps = 1e-9f;
  float sq = ox*ox + oy*oy + oz*oz;
  float u = 1.f - sq;
  win = fminf(fmaxf(u*u*u, 0.f), 1.f);
  float norm = sqrtf(sq + eps);
  float rxy2 = ox*ox + oy*oy;
  bool polar = (1.25f*oz*oz > rxy2);
  float s_p = sqrtf(3.f*norm/(norm + fabsf(oz) + eps));
  float s_n = norm / sqrtf(rxy2 + eps);
  float s = polar ? s_p : s_n;
  float xc = ox*s, yc = oy*s;
  float zc = polar ? sgnf(oz)*norm : 1.5f*oz;
  if(sq < 1e-12f){ xc = 0.f; yc = 0.f; zc = 0.f; }
  float r = sqrtf(xc*xc + yc*yc + eps);
  bool c1 = fabsf(xc) >= fabsf(yc);
  float xs = (fabsf(xc) < eps) ? eps : xc;
  float ys = (fabsf(yc) < eps) ? eps : yc;
  const float fop = 1.2732395447351628f; // float32(4/pi)
  float a = c1 ? sgnf(xc)*r : sgnf(yc)*r*fop*atanf(xc/ys);
  float b = c1 ? sgnf(xc)*r*fop*atanf(yc/xs) : sgnf(yc)*r;
  if(xc*xc + yc*yc < 1e-12f){ a = 0.f; b = 0.f; }
  float g0 = fminf(fmaxf((a *0.5f+0.5f)*3.f, 0.f), 3.f);
  float g1 = fminf(fmaxf((b *0.5f+0.5f)*3.f, 0.f), 3.f);
  float g2 = fminf(fmaxf((zc*0.5f+0.5f)*3.f, 0.f), 3.f);
  float f00 = floorf(g0), f01 = floorf(g1), f02 = floorf(g2);
  t0 = g0 - f00; t1 = g1 - f01; t2 = g2 - f02;
  f0p = (int)f00 | ((int)f01 << 2) | ((int)f02 << 4);
}

// ---------------- scatter: one node per block; channel-ownership -> race-free ----------------
// NG=2 (CIN<=64): two groups (one wave each) with private B copies, edges interleaved.
// NG=1 (CIN>64): single group, threads own disjoint channels, all edges.
// OUT3=1: fused cout=3 GEMV epilogue (layer 3) -> accumulates into out, B unused.
template<int CIN, int NG, int RELU, int OUT3>
__global__ __launch_bounds__(128) void k_scat(
    const float* __restrict__ feat, const float* __restrict__ pos,
    const int* __restrict__ edst, const int* __restrict__ row_start,
    float* __restrict__ B, int node_base,
    const float* __restrict__ W3, float* __restrict__ out)
{
  constexpr int BSZ = KK*CIN;
  __shared__ __align__(16) float Bl[NG*BSZ];
  __shared__ float g_win[128], g_t0[128], g_t1[128], g_t2[128];
  __shared__ int   g_f0[128], g_dst[128];
  const int tid  = threadIdx.x;
  const int node = node_base + blockIdx.x;

  for(int j = tid*4; j < NG*BSZ; j += 512)
    *(float4*)&Bl[j] = make_float4(0.f,0.f,0.f,0.f);

  const int e0 = row_start[node], e1 = row_start[node+1];
  const float px = pos[node*3+0], py = pos[node*3+1], pz = pos[node*3+2];

  const int g = (NG==2) ? (tid>>6) : 0;
  const int c = (NG==2) ? (tid&63) : tid;
  const bool act = (c < CIN);
  float* Bp = Bl + g*BSZ;
  __syncthreads();

  for(int eb = e0; eb < e1; eb += 128){
    const int m = min(128, e1 - eb);
    if(tid < m){
      const int e = eb + tid;
      const int d = edst[e];
      float ox = (pos[d*3+0]-px)/RADF;
      float oy = (pos[d*3+1]-py)/RADF;
      float oz = (pos[d*3+2]-pz)/RADF;
      float win, t0, t1, t2; int f0p;
      edge_geom(ox, oy, oz, win, t0, t1, t2, f0p);
      g_dst[tid]=d; g_win[tid]=win; g_t0[tid]=t0; g_t1[tid]=t1; g_t2[tid]=t2; g_f0[tid]=f0p;
    }
    __syncthreads();
    if(act){
      for(int j = (NG==2 ? g : 0); j < m; j += NG){
        const float win = g_win[j];
        if(win <= 0.f) continue;
        const float t0 = g_t0[j], t1 = g_t1[j], t2 = g_t2[j];
        const int f0 = g_f0[j];
        float v = feat[(size_t)g_dst[j]*CIN + c];
        if(RELU) v = fmaxf(v, 0.f);
        const int i0 = f0 & 3, i1 = (f0>>2) & 3, i2 = f0 >> 4;
        const int i0p = min(i0+1,3), i1p = min(i1+1,3), i2p = min(i2+1,3);
        const float wx0 = win*(1.f-t0), wx1 = win*t0;
        const float wy0 = 1.f-t1, wy1 = t1;
        const float wz0 = 1.f-t2, wz1 = t2;
        Bp[((i0 <<4)|(i1 <<2)|i2 )*CIN + c] += (wx0*wy0*wz0) * v;
        Bp[((i0 <<4)|(i1 <<2)|i2p)*CIN + c] += (wx0*wy0*wz1) * v;
        Bp[((i0 <<4)|(i1p<<2)|i2 )*CIN + c] += (wx0*wy1*wz0) * v;
        Bp[((i0 <<4)|(i1p<<2)|i2p)*CIN + c] += (wx0*wy1*wz1) * v;
        Bp[((i0p<<4)|(i1 <<2)|i2 )*CIN + c] += (wx1*wy0*wz0) * v;
        Bp[((i0p<<4)|(i1 <<2)|i2p)*CIN + c] += (wx1*wy0*wz1) * v;
        Bp[((i0p<<4)|(i1p<<2)|i2 )*CIN + c] += (wx1*wy1*wz0) * v;
        Bp[((i0p<<4)|(i1p<<2)|i2p)*CIN + c] += (wx1*wy1*wz1) * v;
      }
    }
    __syncthreads();
  }

  if(!OUT3){
    float* Bg = B + (size_t)blockIdx.x*BSZ;
    for(int j = tid*4; j < BSZ; j += 512){
      float4 a = *(const float4*)&Bl[j];
      if(NG==2){
        float4 b2 = *(const float4*)&Bl[BSZ+j];
        a.x+=b2.x; a.y+=b2.y; a.z+=b2.z; a.w+=b2.w;
      }
      *(float4*)&Bg[j] = a;
    }
  } else {
    // fused cout=3 GEMV: out[node] += (sum_j B[j] * W3[j,0..2]) / 128
    float s0=0.f, s1=0.f, s2=0.f;
    for(int j = tid; j < BSZ; j += 128){
      float v = Bl[j];
      if(NG==2) v += Bl[BSZ+j];
      s0 = fmaf(v, W3[j*3+0], s0);
      s1 = fmaf(v, W3[j*3+1], s1);
      s2 = fmaf(v, W3[j*3+2], s2);
    }
    g_win[tid]=s0; g_t0[tid]=s1; g_t1[tid]=s2;
    __syncthreads();
    for(int st = 64; st > 0; st >>= 1){
      if(tid < st){ g_win[tid]+=g_win[tid+st]; g_t0[tid]+=g_t0[tid+st]; g_t1[tid]+=g_t1[tid+st]; }
      __syncthreads();
    }
    if(tid == 0 && node < NREAL){
      out[node*3+0] += g_win[0]*(1.f/128.f);
      out[node*3+1] += g_t0[0]*(1.f/128.f);
      out[node*3+2] += g_t1[0]*(1.f/128.f);
    }
  }
}

// ---- GEMM, no atomics: P[s][node][64] = sum_{k in split s} A[row,k]*W[k,o]
// 64x64 tile, BK=16, 256 threads, 4x4 outputs/thread.
__global__ __launch_bounds__(256) void k_gemm2(
    const float* __restrict__ A, const float* __restrict__ W,
    float* __restrict__ P, int M, int Kd, int node_base, int ktiles_per)
{
  __shared__ __align__(16) float As[16][68];   // [k][row], padded: stores 2-way, reads broadcast
  __shared__ __align__(16) float Ws[16][64];   // [k][col]
  const int tid = threadIdx.x;
  const int mbase = blockIdx.x * 64;
  const int s = blockIdx.y;
  const int kt0 = s * ktiles_per * 16;
  const int kt1 = min(Kd, kt0 + ktiles_per*16);
  const int ty = tid >> 4, tx = tid & 15;
  const int arow = tid >> 2, ako = (tid & 3) * 4;
  const int wk = tid >> 4,  wc = (tid & 15) * 4;

  float acc[4][4];
  #pragma unroll
  for(int i=0;i<4;++i)
    #pragma unroll
    for(int j=0;j<4;++j) acc[i][j] = 0.f;

  for(int kt = kt0; kt < kt1; kt += 16){
    float4 av = make_float4(0.f,0.f,0.f,0.f);
    const int grow = mbase + arow;
    if(grow < M) av = *(const float4*)(A + (size_t)grow*Kd + kt + ako);
    const float4 wv = *(const float4*)(W + (size_t)(kt + wk)*64 + wc);
    As[ako+0][arow]=av.x; As[ako+1][arow]=av.y; As[ako+2][arow]=av.z; As[ako+3][arow]=av.w;
    *(float4*)&Ws[wk][wc] = wv;
    __syncthreads();
    #pragma unroll
    for(int kk = 0; kk < 16; ++kk){
      const float4 a = *(const float4*)&As[kk][ty*4];
      const float4 b = *(const float4*)&Ws[kk][tx*4];
      const float aa[4] = {a.x,a.y,a.z,a.w};
      const float bb[4] = {b.x,b.y,b.z,b.w};
      #pragma unroll
      for(int i=0;i<4;++i)
        #pragma unroll
        for(int j=0;j<4;++j) acc[i][j] = fmaf(aa[i], bb[j], acc[i][j]);
    }
    __syncthreads();
  }

  #pragma unroll
  for(int i=0;i<4;++i){
    const int row = mbase + ty*4 + i;
    if(row < M)
      *(float4*)(P + ((size_t)s*NPTS + node_base + row)*64 + tx*4) = *(float4*)&acc[i][0];
  }
}

// ---- combine partials: x[node*ldout+colofs+o] += sum_s P[s][node][o]
template<int S>
__global__ void k_combine(const float* __restrict__ P, float* __restrict__ x,
                          int ldout, int colofs)
{
  int idx = blockIdx.x*blockDim.x + threadIdx.x;
  if(idx >= NPTS*16) return;
  int node = idx >> 4, c4 = (idx & 15) * 4;
  float4 s = *(const float4*)(P + (size_t)node*64 + c4);
  #pragma unroll
  for(int k=1;k<S;++k){
    float4 t = *(const float4*)(P + ((size_t)k*NPTS + node)*64 + c4);
    s.x+=t.x; s.y+=t.y; s.z+=t.z; s.w+=t.w;
  }
  float* xp = x + (size_t)node*ldout + colofs + c4;
  float4 o = *(float4*)xp;
  o.x+=s.x; o.y+=s.y; o.z+=s.z; o.w+=s.w;
  *(float4*)xp = o;
}

// ---------------- dense paths ----------------
__global__ void k_dense0(const float* __restrict__ f, const float* __restrict__ dW,
                         const float* __restrict__ db, const float* __restrict__ cb0,
                         float* __restrict__ out)
{
  int idx = blockIdx.x*blockDim.x + threadIdx.x;
  if(idx >= NPTS*96) return;
  int i = idx/96, c = idx - i*96;
  if(c < 64){ out[idx] = cb0[c]; return; }
  int o = c - 64;
  float s = db[o];
  const float* row = f + (size_t)i*13;
  #pragma unroll
  for(int j=0;j<13;++j) s = fmaf(row[j], dW[j*32+o], s);
  out[idx] = s;
}

__global__ void k_dense(const float* __restrict__ in, int cin,
                        const float* __restrict__ dW, const float* __restrict__ db,
                        const float* __restrict__ cb, const float* __restrict__ resid,
                        float* __restrict__ out)
{
  int idx = blockIdx.x*blockDim.x + threadIdx.x;
  if(idx >= NPTS*64) return;
  int i = idx >> 6, o = idx & 63;
  float s = db[o] + cb[o];
  if(resid) s += resid[idx];
  const float* row = in + (size_t)i*cin;
  for(int c=0;c<cin;++c) s = fmaf(fmaxf(row[c],0.f), dW[c*64+o], s);
  out[idx] = s;
}

__global__ void k_dense3(const float* __restrict__ x2, const float* __restrict__ dW,
                         const float* __restrict__ db, const float* __restrict__ cb,
                         float* __restrict__ out)
{
  int idx = blockIdx.x*blockDim.x + threadIdx.x;
  if(idx >= NREAL*3) return;
  int i = idx/3, o = idx - i*3;
  float s = db[o] + cb[o];
  const float* row = x2 + (size_t)i*64;
  for(int c=0;c<64;++c) s = fmaf(fmaxf(row[c],0.f), dW[c*3+o], s);
  out[idx] = s * (1.f/128.f);
}

// ---------------- host ----------------
static inline size_t alup(size_t x){ return (x + 255) & ~(size_t)255; }

static inline int calc_rows(size_t bcap, int cin){
  size_t perrow = (size_t)KK * cin * 4;
  size_t r = (perrow > 0) ? bcap / perrow : 0;
  if(r >= (size_t)NPTS) return NPTS;
  r = (r / 128) * 128;
  if(r < 128) r = 128;
  return (int)r;
}

extern "C" void kernel_launch(void* const* d_in, const int* in_sizes, int n_in,
                              void* d_out, int out_size, void* d_ws, size_t ws_size,
                              hipStream_t stream)
{
  const float* pos   = (const float*)d_in[0];
  const float* feats = (const float*)d_in[1];
  const int*   esrc  = (const int*)d_in[2];
  const int*   edst  = (const int*)d_in[3];
  const float* c0w = (const float*)d_in[4];
  const float* c0b = (const float*)d_in[5];
  const float* d0w = (const float*)d_in[6];
  const float* d0b = (const float*)d_in[7];
  const float* c1w = (const float*)d_in[8];
  const float* c1b = (const float*)d_in[9];
  const float* d1w = (const float*)d_in[10];
  const float* d1b = (const float*)d_in[11];
  const float* c2w = (const float*)d_in[12];
  const float* c2b = (const float*)d_in[13];
  const float* d2w = (const float*)d_in[14];
  const float* d2b = (const float*)d_in[15];
  const float* c3w = (const float*)d_in[16];
  const float* c3b = (const float*)d_in[17];
  const float* d3w = (const float*)d_in[18];
  const float* d3b = (const float*)d_in[19];
  float* out = (float*)d_out;

  char* w = (char*)d_ws;
  size_t off = 0;
  float* f  = (float*)(w+off); off += alup((size_t)NPTS*13*4);
  float* x0 = (float*)(w+off); off += alup((size_t)NPTS*96*4);
  float* x1 = (float*)(w+off); off += alup((size_t)NPTS*64*4);
  float* x2 = (float*)(w+off); off += alup((size_t)NPTS*64*4);
  int* row_start = (int*)(w+off); off += alup((size_t)(NPTS+1)*4);
  int* ereal = (int*)(w+off);     off += alup(16);
  float* P  = (float*)(w+off); off += alup((size_t)4*NPTS*64*4);  // split-K partials
  float* B = (float*)(w+off);
  size_t bcap = (ws_size > off) ? (ws_size - off) : 0;

  k_find_ereal<<<1,1,0,stream>>>(edst, ereal);
  k_csr<<<(NPTS+1+255)/256,256,0,stream>>>(esrc, ereal, row_start);
  k_build_f<<<(NPTS*13+255)/256,256,0,stream>>>(feats, f);

  // ---- layer 0: x0[:,0:64] = cconv0(f)+c0b ; x0[:,64:96] = f@d0w+d0b
  k_dense0<<<(NPTS*96+255)/256,256,0,stream>>>(f, d0w, d0b, c0b, x0);
  {
    int rows = calc_rows(bcap, 13);
    for(int base = 0; base < NPTS; base += rows){
      int m = (NPTS - base < rows) ? (NPTS - base) : rows;
      k_scat<13,2,0,0><<<m,128,0,stream>>>(f, pos, edst, row_start, B, base, nullptr, nullptr);
      k_gemm2<<<dim3((m+63)/64, 2),256,0,stream>>>(B, c0w, P, m, 832, base, 26);
    }
    k_combine<2><<<(NPTS*16+255)/256,256,0,stream>>>(P, x0, 96, 0);
  }

  // ---- layer 1: x1 = cconv1(relu(x0)) + relu(x0)@d1w + d1b + c1b
  k_dense<<<(NPTS*64+255)/256,256,0,stream>>>(x0, 96, d1w, d1b, c1b, nullptr, x1);
  {
    int rows = calc_rows(bcap, 96);
    for(int base = 0; base < NPTS; base += rows){
      int m = (NPTS - base < rows) ? (NPTS - base) : rows;
      k_scat<96,1,1,0><<<m,128,0,stream>>>(x0, pos, edst, row_start, B, base, nullptr, nullptr);
      k_gemm2<<<dim3((m+63)/64, 4),256,0,stream>>>(B, c1w, P, m, 6144, base, 96);
    }
    k_combine<4><<<(NPTS*16+255)/256,256,0,stream>>>(P, x1, 64, 0);
  }

  // ---- layer 2: x2 = cconv2(relu(x1)) + relu(x1)@d2w + d2b + c2b + x1 (residual)
  k_dense<<<(NPTS*64+255)/256,256,0,stream>>>(x1, 64, d2w, d2b, c2b, x1, x2);
  {
    int rows = calc_rows(bcap, 64);
    for(int base = 0; base < NPTS; base += rows){
      int m = (NPTS - base < rows) ? (NPTS - base) : rows;
      k_scat<64,2,1,0><<<m,128,0,stream>>>(x1, pos, edst, row_start, B, base, nullptr, nullptr);
      k_gemm2<<<dim3((m+63)/64, 4),256,0,stream>>>(B, c2w, P, m, 4096, base, 64);
    }
    k_combine<4><<<(NPTS*16+255)/256,256,0,stream>>>(P, x2, 64, 0);
  }

  // ---- layer 3 (fused): out = dense3 part, then scatter adds conv3 GEMV directly
  k_dense3<<<(NREAL*3+255)/256,256,0,stream>>>(x2, d3w, d3b, c3b, out);
  k_scat<64,2,1,1><<<NPTS,128,0,stream>>>(x2, pos, edst, row_start, nullptr, 0, c3w, out);
}